// Round 8
// baseline (256.024 us; speedup 1.0000x reference)
//
#include <hip/hip_runtime.h>
#include <hip/hip_bf16.h>
#include <math.h>

#define WAVE 64

// Champion structure (R1, 223 us) with ONE change: chunk_hist + serial
// scan_hist replaced by a single ballot-based kernel (64 waves, wave=expert)
// that produces the identical base1/base2/total1 arrays with no serial
// global-latency chain. Everything else byte-identical to R1.

// ---------------- Kernel A: per-token softmax + top1/top2 ----------------
__global__ void router_softmax_top2(const float* __restrict__ x,
                                    int* __restrict__ top1,
                                    int* __restrict__ top2,
                                    float* __restrict__ w1,
                                    float* __restrict__ w2,
                                    int S) {
    const int wavesPerBlock = blockDim.x >> 6;
    const int wid  = threadIdx.x >> 6;
    const int lane = threadIdx.x & 63;
    const int s = blockIdx.x * wavesPerBlock + wid;
    if (s >= S) return;

    float v = x[(size_t)s * 64 + lane];

    // argmax with lowest-index tiebreak (matches jnp.argmax)
    float bv = v; int bi = lane;
    #pragma unroll
    for (int off = 32; off >= 1; off >>= 1) {
        float ov = __shfl_xor(bv, off, WAVE);
        int   oi = __shfl_xor(bi, off, WAVE);
        if (ov > bv || (ov == bv && oi < bi)) { bv = ov; bi = oi; }
    }
    const float m = bv;
    const int t1 = bi;

    // fp32 softmax
    float e = expf(v - m);
    float sum = e;
    #pragma unroll
    for (int off = 32; off >= 1; off >>= 1) sum += __shfl_xor(sum, off, WAVE);
    const float p = e / sum;

    // second argmax with top1 masked out
    float v2 = (lane == t1) ? -INFINITY : v;
    float bv2 = v2; int bi2 = lane;
    #pragma unroll
    for (int off = 32; off >= 1; off >>= 1) {
        float ov = __shfl_xor(bv2, off, WAVE);
        int   oi = __shfl_xor(bi2, off, WAVE);
        if (ov > bv2 || (ov == bv2 && oi < bi2)) { bv2 = ov; bi2 = oi; }
    }
    const int t2 = bi2;

    const float p1 = __shfl(p, t1, WAVE);
    const float p2 = __shfl(p, t2, WAVE);

    if (lane == 0) {
        top1[s] = t1; top2[s] = t2;
        w1[s] = p1;   w2[s] = p2;
    }
}

// ---------------- Kernel B: per-expert ballot bases ----------------
// 64 waves total (16 blocks x 256); wave = expert e. One sweep over all
// tokens: base{1,2}[c*64+e] = running count of expert-e tokens before
// chunk c (exclusive scan), total1[e] = full top-1 count. All loads are
// independent across iterations -> pipelined, no serial scan.
__global__ void __launch_bounds__(256)
ballot_bases(const int* __restrict__ top1,
             const int* __restrict__ top2,
             int* __restrict__ base1,
             int* __restrict__ base2,
             int* __restrict__ total1,
             int nchunks) {
    const int e    = (blockIdx.x * blockDim.x + threadIdx.x) >> 6;
    const int lane = threadIdx.x & 63;

    int run1 = 0, run2 = 0;
    #pragma unroll 4
    for (int c = 0; c < nchunks; ++c) {
        const int s = c * 64 + lane;
        const unsigned long long m1 = __ballot(top1[s] == e);
        const unsigned long long m2 = __ballot(top2[s] == e);
        if (lane == 0) {
            base1[c * 64 + e] = run1;
            base2[c * 64 + e] = run2;
        }
        run1 += __popcll(m1);
        run2 += __popcll(m2);
    }
    if (lane == 0) total1[e] = run1;
}

// ---------------- Kernel C: final ranks + scatter (identical to R1) -------
__global__ void rank_scatter(const int* __restrict__ top1,
                             const int* __restrict__ top2,
                             const float* __restrict__ w1,
                             const float* __restrict__ w2,
                             const int* __restrict__ base1,
                             const int* __restrict__ base2,
                             const int* __restrict__ total1,
                             float* __restrict__ out,
                             int S, int CAP) {
    const int c = blockIdx.x;
    const int i = threadIdx.x;
    const int s = c * 64 + i;
    const int t1 = top1[s];
    const int t2 = top2[s];

    int cnt1 = 0, cnt2 = 0;
    #pragma unroll 8
    for (int j = 0; j < 64; ++j) {
        const int o1 = __shfl(t1, j, WAVE);
        const int o2 = __shfl(t2, j, WAVE);
        cnt1 += (o1 == t1) && (j < i);
        cnt2 += (o2 == t2) && (j < i);
    }

    const int rank1 = base1[c * 64 + t1] + cnt1;
    const int rank2 = base2[c * 64 + t2] + cnt2 + total1[t2];

    const size_t secoff = (size_t)S * 64 * CAP;
    if (rank1 < CAP) {
        const size_t idx = ((size_t)s * 64 + t1) * CAP + rank1;
        out[idx] = w1[s];
        out[secoff + idx] = 1.0f;
    }
    if (rank2 < CAP) {
        const size_t idx = ((size_t)s * 64 + t2) * CAP + rank2;
        out[idx] = w2[s];
        out[secoff + idx] = 1.0f;
    }
}

extern "C" void kernel_launch(void* const* d_in, const int* in_sizes, int n_in,
                              void* d_out, int out_size, void* d_ws, size_t ws_size,
                              hipStream_t stream) {
    const float* x = (const float*)d_in[0];
    float* out = (float*)d_out;

    const int E = 64;
    const int S = in_sizes[0] / E;            // 8192
    int cap = (int)(2.0 * S / E);
    cap += cap % 2;
    if (cap < 4) cap = 4;                     // 256

    const int nchunks = S / 64;               // 128

    // workspace layout (all 4-byte elements)
    char* w = (char*)d_ws;
    int*   top1   = (int*)w;   w += (size_t)S * 4;
    int*   top2   = (int*)w;   w += (size_t)S * 4;
    float* w1     = (float*)w; w += (size_t)S * 4;
    float* w2     = (float*)w; w += (size_t)S * 4;
    int*   base1  = (int*)w;   w += (size_t)nchunks * 64 * 4;
    int*   base2  = (int*)w;   w += (size_t)nchunks * 64 * 4;
    int*   total1 = (int*)w;   w += 64 * 4;

    // 1) zero the dense output FIRST (champion ordering)
    hipMemsetAsync(d_out, 0, (size_t)out_size * sizeof(float), stream);

    // 2) softmax + top2 (4 waves per 256-thread block)
    {
        const int wavesPerBlock = 4;
        const int blocks = (S + wavesPerBlock - 1) / wavesPerBlock;
        router_softmax_top2<<<blocks, wavesPerBlock * 64, 0, stream>>>(
            x, top1, top2, w1, w2, S);
    }

    // 3) ballot bases (replaces chunk_hist + serial scan_hist)
    ballot_bases<<<16, 256, 0, stream>>>(top1, top2, base1, base2, total1,
                                         nchunks);

    // 4) ranks + scatter
    rank_scatter<<<nchunks, 64, 0, stream>>>(top1, top2, w1, w2,
                                             base1, base2, total1,
                                             out, S, cap);
}

// Round 9
// 194.969 us; speedup vs baseline: 1.3132x; 1.3132x over previous
//
#include <hip/hip_runtime.h>
#include <hip/hip_bf16.h>
#include <math.h>

#define WAVE 64

// R1 champion (223 us) with ONE change: scan_hist fused into rank_scatter.
// Each rank block re-scans the hist arrays itself (coalesced, pipelined
// loads; no serial cross-chunk dependency, no extra dispatch).
// Empirical rule from R4/R5/R6/R8: avoid the 16-block ballot shape (+30 us).

// ---------------- Kernel A: per-token softmax + top1/top2 ----------------
__global__ void router_softmax_top2(const float* __restrict__ x,
                                    int* __restrict__ top1,
                                    int* __restrict__ top2,
                                    float* __restrict__ w1,
                                    float* __restrict__ w2,
                                    int S) {
    const int wavesPerBlock = blockDim.x >> 6;
    const int wid  = threadIdx.x >> 6;
    const int lane = threadIdx.x & 63;
    const int s = blockIdx.x * wavesPerBlock + wid;
    if (s >= S) return;

    float v = x[(size_t)s * 64 + lane];

    // argmax with lowest-index tiebreak (matches jnp.argmax)
    float bv = v; int bi = lane;
    #pragma unroll
    for (int off = 32; off >= 1; off >>= 1) {
        float ov = __shfl_xor(bv, off, WAVE);
        int   oi = __shfl_xor(bi, off, WAVE);
        if (ov > bv || (ov == bv && oi < bi)) { bv = ov; bi = oi; }
    }
    const float m = bv;
    const int t1 = bi;

    // fp32 softmax
    float e = expf(v - m);
    float sum = e;
    #pragma unroll
    for (int off = 32; off >= 1; off >>= 1) sum += __shfl_xor(sum, off, WAVE);
    const float p = e / sum;

    // second argmax with top1 masked out
    float v2 = (lane == t1) ? -INFINITY : v;
    float bv2 = v2; int bi2 = lane;
    #pragma unroll
    for (int off = 32; off >= 1; off >>= 1) {
        float ov = __shfl_xor(bv2, off, WAVE);
        int   oi = __shfl_xor(bi2, off, WAVE);
        if (ov > bv2 || (ov == bv2 && oi < bi2)) { bv2 = ov; bi2 = oi; }
    }
    const int t2 = bi2;

    const float p1 = __shfl(p, t1, WAVE);
    const float p2 = __shfl(p, t2, WAVE);

    if (lane == 0) {
        top1[s] = t1; top2[s] = t2;
        w1[s] = p1;   w2[s] = p2;
    }
}

// ---------------- Kernel B: per-chunk expert histograms (identical to R1) --
__global__ void chunk_hist(const int* __restrict__ top1,
                           const int* __restrict__ top2,
                           int* __restrict__ hist1,
                           int* __restrict__ hist2) {
    const int c = blockIdx.x;
    const int lane = threadIdx.x;
    const int t1 = top1[c * 64 + lane];
    const int t2 = top2[c * 64 + lane];
    int c1 = 0, c2 = 0;
    #pragma unroll 8
    for (int j = 0; j < 64; ++j) {
        c1 += (__shfl(t1, j, WAVE) == lane);
        c2 += (__shfl(t2, j, WAVE) == lane);
    }
    hist1[c * 64 + lane] = c1;
    hist2[c * 64 + lane] = c2;
}

// ---------------- Kernel C: fused scan + ranks + scatter ----------------
// One 64-lane block per chunk. Thread i = expert i for the scan phase:
// sweeps hist arrays (coalesced across the wave, loads independent ->
// pipelined), accumulating this chunk's exclusive base and the full
// pre-drop top-1 totals. Bases for each token's experts fetched via shfl.
__global__ void rank_scatter(const int* __restrict__ top1,
                             const int* __restrict__ top2,
                             const float* __restrict__ w1,
                             const float* __restrict__ w2,
                             const int* __restrict__ hist1,
                             const int* __restrict__ hist2,
                             float* __restrict__ out,
                             int S, int CAP, int nchunks) {
    const int c = blockIdx.x;
    const int i = threadIdx.x;
    const int s = c * 64 + i;

    // scan phase: thread i accumulates expert-i counts
    int b1 = 0, b2 = 0, tot1 = 0;
    #pragma unroll 8
    for (int cc = 0; cc < nchunks; ++cc) {
        const int h1 = hist1[cc * 64 + i];
        const int h2 = hist2[cc * 64 + i];
        const int lt = (cc < c);
        b1   += lt ? h1 : 0;
        b2   += lt ? h2 : 0;
        tot1 += h1;                 // full pre-drop top-1 count of expert i
    }

    const int t1 = top1[s];
    const int t2 = top2[s];

    // within-chunk stable counts
    int cnt1 = 0, cnt2 = 0;
    #pragma unroll 8
    for (int j = 0; j < 64; ++j) {
        const int o1 = __shfl(t1, j, WAVE);
        const int o2 = __shfl(t2, j, WAVE);
        cnt1 += (o1 == t1) && (j < i);
        cnt2 += (o2 == t2) && (j < i);
    }

    const int rank1 = __shfl(b1, t1, WAVE) + cnt1;
    const int rank2 = __shfl(b2, t2, WAVE) + cnt2 + __shfl(tot1, t2, WAVE);

    const size_t secoff = (size_t)S * 64 * CAP;
    if (rank1 < CAP) {
        const size_t idx = ((size_t)s * 64 + t1) * CAP + rank1;
        out[idx] = w1[s];
        out[secoff + idx] = 1.0f;
    }
    if (rank2 < CAP) {
        const size_t idx = ((size_t)s * 64 + t2) * CAP + rank2;
        out[idx] = w2[s];
        out[secoff + idx] = 1.0f;
    }
}

extern "C" void kernel_launch(void* const* d_in, const int* in_sizes, int n_in,
                              void* d_out, int out_size, void* d_ws, size_t ws_size,
                              hipStream_t stream) {
    const float* x = (const float*)d_in[0];
    float* out = (float*)d_out;

    const int E = 64;
    const int S = in_sizes[0] / E;            // 8192
    int cap = (int)(2.0 * S / E);
    cap += cap % 2;
    if (cap < 4) cap = 4;                     // 256

    const int nchunks = S / 64;               // 128

    // workspace layout (all 4-byte elements)
    char* w = (char*)d_ws;
    int*   top1   = (int*)w;   w += (size_t)S * 4;
    int*   top2   = (int*)w;   w += (size_t)S * 4;
    float* w1     = (float*)w; w += (size_t)S * 4;
    float* w2     = (float*)w; w += (size_t)S * 4;
    int*   hist1  = (int*)w;   w += (size_t)nchunks * 64 * 4;
    int*   hist2  = (int*)w;   w += (size_t)nchunks * 64 * 4;

    // 1) zero the dense output FIRST (champion ordering)
    hipMemsetAsync(d_out, 0, (size_t)out_size * sizeof(float), stream);

    // 2) softmax + top2 (4 waves per 256-thread block)
    {
        const int wavesPerBlock = 4;
        const int blocks = (S + wavesPerBlock - 1) / wavesPerBlock;
        router_softmax_top2<<<blocks, wavesPerBlock * 64, 0, stream>>>(
            x, top1, top2, w1, w2, S);
    }

    // 3) per-chunk histograms
    chunk_hist<<<nchunks, 64, 0, stream>>>(top1, top2, hist1, hist2);

    // 4) fused scan + ranks + scatter
    rank_scatter<<<nchunks, 64, 0, stream>>>(top1, top2, w1, w2,
                                             hist1, hist2, out,
                                             S, cap, nchunks);
}